// Round 10
// baseline (10.511 us; speedup 1.0000x reference)
//
#include <hip/hip_runtime.h>

#define NUM_PAGES 1048576
#define TPP 32
#define SLOTS 256
#define MPPS 4096
#define NBLK 512
#define NTHR 256
// block b copies int4 giA=b*512+t and giB=giA+256 of ps and pm:
//   ps pages [b*2048, +2048);  pm cols [(b&1)*2048, +2048) of slot row b>>1.
// Wide scan round: thread t holds pages {t*4..+4} of chunks 0,1,2 (0..3071).

__global__ __launch_bounds__(NTHR) void fused(
    const int* __restrict__ ps, const int* __restrict__ pm,
    const int* __restrict__ seq, const int* __restrict__ npu,
    const int* __restrict__ cp, int* __restrict__ out)
{
    const int t = threadIdx.x, b = blockIdx.x;
    const int lane = t & 63, wave = t >> 6;

    int* out_ps  = out;                     // NUM_PAGES
    int* out_pm  = out + NUM_PAGES;         // SLOTS*MPPS == NUM_PAGES
    int* out_seq = out + 2 * NUM_PAGES;
    int* out_npu = out_seq + SLOTS;
    int* out_cp  = out_npu + SLOTS;
    int* out_cpp = out_cp + SLOTS;

    __shared__ int s_w[12];         // 4 waves x 3 chunks partial sums
    __shared__ int s_free[SLOTS];   // all blocks: rank -> page
    __shared__ int s_rank[SLOTS];   // block 0: slot -> rank or -1
    __shared__ int s_cpo[SLOTS];    // block 0: original current_page

    const int4* ps4 = reinterpret_cast<const int4*>(ps);
    const int4* pm4 = reinterpret_cast<const int4*>(pm);
    const int giA = b * (2 * NTHR) + t;
    const int giB = giA + NTHR;

    // ---- issue all loads up front (4 copy loads/array-pair in flight) ------
    const int4 sq4 = reinterpret_cast<const int4*>(seq)[lane];
    const int4 cq4 = reinterpret_cast<const int4*>(cp)[lane];
    const int4 nu4 = reinterpret_cast<const int4*>(npu)[lane];
    const int4 pc0 = ps4[t];                // pages 0..1023
    const int4 pc1 = ps4[NTHR + t];         // pages 1024..2047
    const int4 pc2 = ps4[2 * NTHR + t];     // pages 2048..3071
    const int4 pvA = ps4[giA];
    const int4 pvB = ps4[giB];
    const int4 mvA = pm4[giA];
    const int4 mvB = pm4[giB];

    // ---- copy stores ASAP: stream under the logic (R5-proven pattern) ------
    reinterpret_cast<int4*>(out_ps)[giA] = pvA;
    reinterpret_cast<int4*>(out_ps)[giB] = pvB;
    reinterpret_cast<int4*>(out_pm)[giA] = mvA;
    reinterpret_cast<int4*>(out_pm)[giB] = mvB;

    // ---- slot math, 4 slots/lane, redundant per wave (shfl-only) -----------
    int ns0 = sq4.x + (cq4.x != -1), nn0 = (ns0 + TPP - 1) >> 5;
    int ns1 = sq4.y + (cq4.y != -1), nn1 = (ns1 + TPP - 1) >> 5;
    int ns2 = sq4.z + (cq4.z != -1), nn2 = (ns2 + TPP - 1) >> 5;
    int ns3 = sq4.w + (cq4.w != -1), nn3 = (ns3 + TPP - 1) >> 5;
    int nb = (nn0 > nu4.x ? 1 : 0) | (nn1 > nu4.y ? 2 : 0) |
             (nn2 > nu4.z ? 4 : 0) | (nn3 > nu4.w ? 8 : 0);
    int cnt = __popc(nb), x = cnt;
    #pragma unroll
    for (int o = 1; o < 64; o <<= 1) { int y = __shfl_up(x, o); if (lane >= o) x += y; }
    const int K = __shfl(x, 63);
    const int base_r = x - cnt;
    const int iv0 = (nb & 1) ? base_r : -1;
    const int iv1 = (nb & 2) ? base_r + (nb & 1) : -1;
    const int iv2 = (nb & 4) ? base_r + __popc(nb & 3) : -1;
    const int iv3 = (nb & 8) ? base_r + __popc(nb & 7) : -1;

    if (b == 0 && wave == 0) {              // slot vectors + block-0 tables
        int4 o;
        o.x = ns0; o.y = ns1; o.z = ns2; o.w = ns3;
        reinterpret_cast<int4*>(out_seq)[lane] = o;
        o.x = nn0; o.y = nn1; o.z = nn2; o.w = nn3;
        reinterpret_cast<int4*>(out_npu)[lane] = o;
        o.x = ns0 ? ((ns0 - 1) & 31) : 0;
        o.y = ns1 ? ((ns1 - 1) & 31) : 0;
        o.z = ns2 ? ((ns2 - 1) & 31) : 0;
        o.w = ns3 ? ((ns3 - 1) & 31) : 0;
        reinterpret_cast<int4*>(out_cpp)[lane] = o;
        o.x = iv0; o.y = iv1; o.z = iv2; o.w = iv3;
        reinterpret_cast<int4*>(s_rank)[lane] = o;
        reinterpret_cast<int4*>(s_cpo)[lane] = cq4;
    }

    // my block's pm-patch target: slot b>>1, column npu[slot], that slot's rank
    const int slot_b = b >> 1;
    const int jb = slot_b & 3;
    int my_iv = (jb == 0) ? iv0 : (jb == 1) ? iv1 : (jb == 2) ? iv2 : iv3;
    int my_nu = (jb == 0) ? nu4.x : (jb == 1) ? nu4.y : (jb == 2) ? nu4.z : nu4.w;
    const int tr    = __shfl(my_iv, slot_b >> 2);   // alloc rank, -1 = none
    const int col_b = __shfl(my_nu, slot_b >> 2);   // pm column to patch

    // ---- wide scan: pages 0..3071, one round, 3 interleaved shfl chains ----
    auto fm = [](int4 v) {
        return ((v.x == 0) ? 1 : 0) | ((v.y == 0) ? 2 : 0) |
               ((v.z == 0) ? 4 : 0) | ((v.w == 0) ? 8 : 0);
    };
    int m0 = fm(pc0), m1 = fm(pc1), m2 = fm(pc2);
    if (t == 0) m0 &= ~1;                   // page 0 never allocatable
    int q0 = __popc(m0), q1 = __popc(m1), q2 = __popc(m2);
    int x0 = q0, x1 = q1, x2 = q2;
    #pragma unroll
    for (int o = 1; o < 64; o <<= 1) {
        int y0 = __shfl_up(x0, o), y1 = __shfl_up(x1, o), y2 = __shfl_up(x2, o);
        if (lane >= o) { x0 += y0; x1 += y1; x2 += y2; }
    }
    if (lane == 63) { s_w[wave] = x0; s_w[4 + wave] = x1; s_w[8 + wave] = x2; }
    __syncthreads();                        // barrier 1
    int w0 = 0, w1 = 0, w2 = 0, T0 = 0, T1 = 0, T2 = 0;
    #pragma unroll
    for (int w = 0; w < 4; ++w) {
        int a0 = s_w[w], a1 = s_w[4 + w], a2 = s_w[8 + w];
        if (w < wave) { w0 += a0; w1 += a1; w2 += a2; }
        T0 += a0; T1 += a1; T2 += a2;
    }
    const int pos0 = w0 + x0 - q0;
    const int pos1 = T0 + w1 + x1 - q1;
    const int pos2 = T0 + T1 + w2 + x2 - q2;

    // all blocks: rank -> page table (LDS)
    #pragma unroll
    for (int j = 0; j < 4; ++j) {
        if (m0 & (1 << j)) { int p = pos0 + __popc(m0 & ((1 << j) - 1)); if (p < K) s_free[p] = t * 4 + j; }
        if (m1 & (1 << j)) { int p = pos1 + __popc(m1 & ((1 << j) - 1)); if (p < K) s_free[p] = 1024 + t * 4 + j; }
        if (m2 & (1 << j)) { int p = pos2 + __popc(m2 & ((1 << j) - 1)); if (p < K) s_free[p] = 2048 + t * 4 + j; }
    }

    // ---- generic fallback: frees beyond page 3071 (never hit here) ---------
    int fe_total = T0 + T1 + T2;
    for (int ch = 3; (ch << 10) < NUM_PAGES && fe_total < K; ++ch) {
        int4 v = ps4[(ch << 8) + t];
        int m = fm(v);
        int q = __popc(m), xx = q;
        #pragma unroll
        for (int o = 1; o < 64; o <<= 1) { int y = __shfl_up(xx, o); if (lane >= o) xx += y; }
        if (lane == 63) s_w[wave] = xx;
        __syncthreads();
        int wo = 0, T = 0;
        #pragma unroll
        for (int w = 0; w < 4; ++w) { if (w < wave) wo += s_w[w]; T += s_w[w]; }
        int pos = fe_total + wo + xx - q;
        #pragma unroll
        for (int j = 0; j < 4; ++j) if (m & (1 << j)) {
            int p = pos + __popc(m & ((1 << j) - 1));
            if (p < K) s_free[p] = (ch << 10) + (t << 2) + j;
        }
        fe_total += T;
        __syncthreads();
    }
    const int fe = (fe_total < K) ? fe_total : K;

    __syncthreads();    // barrier 2: s_free visible, copy stores drained

    // ---- patches, strictly by chunk owner (store-based, R5-proven) ---------
    // ps: page f owned by block f>>11 (covers exhausted-pool f=0 -> block 0)
    if (t < K) {
        int f = (t < fe) ? s_free[t] : 0;
        if ((f >> 11) == b) out_ps[f] = 1;
    }
    // pm: slot row b>>1, col half (b&1); one thread issues the store
    if (tr >= 0 && t == 0 && ((col_b >> 11) == (b & 1))) {
        int nfp = (tr < fe) ? s_free[tr] : 0;
        out_pm[slot_b * MPPS + col_b] = nfp;
    }
    // cp vector: block 0
    if (b == 0) {
        int rk = s_rank[t];
        out_cp[t] = (rk >= 0) ? ((rk < fe) ? s_free[rk] : 0) : s_cpo[t];
    }
}

// ---------------------------------------------------------------------------
extern "C" void kernel_launch(void* const* d_in, const int* in_sizes, int n_in,
                              void* d_out, int out_size, void* d_ws, size_t ws_size,
                              hipStream_t stream)
{
    const int* page_status = (const int*)d_in[0];
    const int* page_map    = (const int*)d_in[1];
    const int* seq         = (const int*)d_in[2];
    const int* npu         = (const int*)d_in[3];
    const int* cp          = (const int*)d_in[4];
    // d_in[5] (current_page_position) unused by the reference update.

    fused<<<NBLK, NTHR, 0, stream>>>(
        page_status, page_map, seq, npu, cp, (int*)d_out);
}